// Round 1
// baseline (247.596 us; speedup 1.0000x reference)
//
#include <hip/hip_runtime.h>

// out[N,32] = segment_sum(edge_val[e] * weight[edge_col[e], :], edge_row[e]) + bias
// Baseline: bias-init kernel + one atomicAdd per (edge, feature).

#define FEAT 32

__global__ __launch_bounds__(256) void gnn_init_out(
    const float* __restrict__ bias, float* __restrict__ out, int total) {
    int i = blockIdx.x * blockDim.x + threadIdx.x;
    if (i < total) out[i] = bias[i & (FEAT - 1)];
}

__global__ __launch_bounds__(256) void gnn_scatter(
    const int* __restrict__ edge_row,
    const int* __restrict__ edge_col,
    const float* __restrict__ edge_val,
    const float* __restrict__ weight,
    float* __restrict__ out,
    int num_edges) {
    long long t = (long long)blockIdx.x * blockDim.x + threadIdx.x;
    int e = (int)(t >> 5);          // 32 threads per edge
    int f = (int)(t & (FEAT - 1));  // feature index
    if (e < num_edges) {
        int r = edge_row[e];   // same address across the 32-lane group -> broadcast
        int c = edge_col[e];
        float v = edge_val[e];
        float w = weight[c * FEAT + f];   // coalesced 128B row gather
        atomicAdd(out + r * FEAT + f, v * w);
    }
}

extern "C" void kernel_launch(void* const* d_in, const int* in_sizes, int n_in,
                              void* d_out, int out_size, void* d_ws, size_t ws_size,
                              hipStream_t stream) {
    const int*   edge_row = (const int*)d_in[0];
    const int*   edge_col = (const int*)d_in[1];
    const float* edge_val = (const float*)d_in[2];
    const float* weight   = (const float*)d_in[3];
    const float* bias     = (const float*)d_in[4];
    float* out = (float*)d_out;

    const int E = in_sizes[0];
    const int total = out_size;  // N * 32

    gnn_init_out<<<(total + 255) / 256, 256, 0, stream>>>(bias, out, total);

    long long threads = (long long)E * FEAT;
    int blocks = (int)((threads + 255) / 256);
    gnn_scatter<<<blocks, 256, 0, stream>>>(edge_row, edge_col, edge_val, weight, out, E);
}